// Round 10
// baseline (312.654 us; speedup 1.0000x reference)
//
#include <hip/hip_runtime.h>
#include <hip/hip_bf16.h>

// WindowAttention, round 10 = round 8 + register headroom for a real dbuf.
// R9 post-mortem: the 2-deep QKV dbuf needed ~185 VGPRs but launch_bounds(256,2)
// capped the allocator at 128 (VGPR_Count tracks 256/bound: R5 4->64, R7 3->72,
// R8/R9 2->128) -> spill -> regression. Occupancy is LDS-capped at 2 blocks/CU
// (80 KiB), so launch_bounds(256,1) costs nothing and unlocks the registers.
// Changes vs R8:
//   1) __launch_bounds__(256, 1) on k_fused.
//   2) QKV K-loop: 2-deep A (ds_read) + B (global) double-buffer (R9 FIX2).
//   3) staging identical to R8 (coalesced row reads; known-good).

typedef __attribute__((ext_vector_type(8))) short short8;
typedef __attribute__((ext_vector_type(4))) float f32x4;

#define SCALE 0.17677669529663687f  // (192/6)^-0.5

// ---------------- ws layout ----------------
#define WQF_OFF    0ul
#define WQF_BYTES  (864ul*1024)                  // 6h*12ct*12kt frags
#define WPF_OFF    (WQF_OFF + WQF_BYTES)
#define WPF_BYTES  (144ul*1024)                  // 12ct*12kt frags
#define COMB_OFF   (WPF_OFF + WPF_BYTES)
#define COMB_BYTES (64ul*6*4096*4)
#define WS_NEED    (COMB_OFF + COMB_BYTES)       // ~7.3 MB

__device__ __forceinline__ unsigned short f2bf(float f){
  unsigned u = __builtin_bit_cast(unsigned, f);
  u = u + 0x7fffu + ((u >> 16) & 1u);            // round-to-nearest-even
  return (unsigned short)(u >> 16);
}
__device__ __forceinline__ unsigned long long pack4(float4 v){
  return (unsigned long long)f2bf(v.x) | ((unsigned long long)f2bf(v.y) << 16)
       | ((unsigned long long)f2bf(v.z) << 32) | ((unsigned long long)f2bf(v.w) << 48);
}

// HW bf16 converts (RNE, same as f2bf).
__device__ __forceinline__ unsigned short cvt1(float x){
  unsigned r;
  asm("v_cvt_pk_bf16_f32 %0, %1, %1" : "=v"(r) : "v"(x));
  return (unsigned short)r;
}
__device__ __forceinline__ uint2 pk4(float a, float b, float c, float d){
  unsigned lo, hi;
  asm("v_cvt_pk_bf16_f32 %0, %1, %2" : "=v"(lo) : "v"(a), "v"(b));
  asm("v_cvt_pk_bf16_f32 %0, %1, %2" : "=v"(hi) : "v"(c), "v"(d));
  return make_uint2(lo, hi);
}

// ---------------- prep: weights -> fragments ----------------
__global__ void k0_wfrag(const float* __restrict__ wq_f, const float* __restrict__ wp_f,
                         unsigned short* __restrict__ wqf, unsigned short* __restrict__ wpf){
  int t = blockIdx.x*256 + threadIdx.x;          // exactly 1008*64
  int fragidx = t >> 6, l = t & 63;
  const float* src; unsigned short* dst;
  float sc = 1.0f;
  if (fragidx < 864){
    int h = fragidx/144, rem = fragidx - h*144;
    int ct = rem/12, kt = rem - ct*12;
    int row = (ct>>2)*384 + h*64 + (ct&3)*16 + (l&15);
    src = wq_f + (long)row*384 + kt*32 + (l>>4)*8;
    dst = wqf + (long)fragidx*512 + l*8;
    if (ct < 4) sc = SCALE;                      // fold softmax scale into q-weights
  } else {
    int fid = fragidx - 864;
    int ct = fid/12, kt = fid - ct*12;
    int row = ct*16 + (l&15);
    src = wp_f + (long)row*384 + kt*32 + (l>>4)*8;
    dst = wpf + (long)fid*512 + l*8;
  }
  short8 v;
  #pragma unroll
  for (int e = 0; e < 8; ++e) v[e] = (short)f2bf(src[e] * sc);
  *(short8*)dst = v;
}

// comb[w][h][i][j] = rpb[h][i][j] + mask[w][i][j]; pad cols j>=49 -> -1e30
__global__ void prep_comb(const float* __restrict__ mask, const float* __restrict__ btab,
                          float* __restrict__ comb){
  int idx = blockIdx.x * 256 + threadIdx.x;      // < 64*6*4096
  int j = idx & 63, i = (idx >> 6) & 63, rest = idx >> 12;
  int h = rest % 6, w = rest / 6;
  float v;
  if (i < 49 && j < 49){
    int di = i / 7 - j / 7 + 6;
    int dj = i % 7 - j % 7 + 6;
    v = btab[(di * 13 + dj) * 6 + h] + mask[(w * 49 + i) * 49 + j];
  } else {
    v = (j >= 49) ? -1e30f : 0.0f;
  }
  comb[idx] = v;
}

// ---------------- fused kernel ----------------
// LDS 80 KiB: A-frags @0 (48K, lives whole kernel), q@49152, k@57344,
// vt@65536 (XOR-swizzled [64][64] bf16), obuf @73728 (8K, O in frag layout).
__device__ __forceinline__ int swz(int r, int b){ return b ^ ((r & 7) << 4); }
__device__ __forceinline__ int a_q (int r, int c){ return 49152 + swz(r, r*128 + c*2); }
__device__ __forceinline__ int a_k (int r, int c){ return 57344 + swz(r, r*128 + c*2); }
__device__ __forceinline__ int a_vt(int r, int c){ return 65536 + swz(r, r*128 + c*2); }
#define OBUF 73728

__global__ __launch_bounds__(256, 1)
void k_fused(const float* __restrict__ x, const float* __restrict__ y,
             const unsigned short* __restrict__ wqf, const unsigned short* __restrict__ wpf,
             const float* __restrict__ bqkv, const float* __restrict__ bproj,
             const float* __restrict__ comb, float* __restrict__ out){
  __shared__ __align__(16) unsigned char smem[81920];
  const int win = blockIdx.x;
  const int tid = threadIdx.x, w = tid>>6, l = tid&63, l15 = l&15, lg = l>>4;

  // ---- stage concat(x,y) -> A-frags in LDS (R8 pattern: coalesced reads) ----
  // A[r][c] -> byte (c>>5)*4096 + (r>>4)*1024 + ((r&15) + ((c>>3)&3)*16)*16 + (c&7)*2
  for (int t = tid; t < 2352; t += 256){
    int r = t / 48, c8 = t - r*48;               // r<49, c8<48
    int c = c8*8;
    const float* src = (c < 192) ? (x + ((long)win*49 + r)*192 + c)
                                 : (y + ((long)win*49 + r)*192 + (c - 192));
    float4 f0 = *(const float4*)src, f1 = *(const float4*)(src + 4);
    uint2 lo = pk4(f0.x, f0.y, f0.z, f0.w);
    uint2 hi = pk4(f1.x, f1.y, f1.z, f1.w);
    uint4 vv = make_uint4(lo.x, lo.y, hi.x, hi.y);
    int addr = (c8>>2)*4096 + (r>>4)*1024 + (((r&15) + (c8&3)*16))*16;
    *(uint4*)(smem + addr) = vv;
  }
  for (int t = tid; t < 720; t += 256){          // zero rows 49..63
    int rr = t / 48, c8 = t - rr*48;
    int r = 49 + rr;
    int addr = (c8>>2)*4096 + (r>>4)*1024 + (((r&15) + (c8&3)*16))*16;
    *(uint4*)(smem + addr) = make_uint4(0,0,0,0);
  }

  // proj accumulators: bias in C-init, live across the head loop
  int np[3];
  f32x4 pacc[4][3];
  #pragma unroll
  for (int nt = 0; nt < 3; ++nt){
    np[nt] = w*48 + nt*16 + l15;
    float bv = bproj[np[nt]];
    #pragma unroll
    for (int mt = 0; mt < 4; ++mt)
      #pragma unroll
      for (int j = 0; j < 4; ++j) pacc[mt][nt][j] = bv;
  }

  __syncthreads();   // A-panel staged

  #pragma unroll 1
  for (int h = 0; h < 6; ++h){
    // comb tile prefetch (consumed post-QK^T; hides under the GEMM)
    const float* cb = comb + ((long)((win & 63)*6 + h))*4096 + (w*16 + l15)*64 + lg*4;
    float4 cbv[4];
    #pragma unroll
    for (int nt = 0; nt < 4; ++nt) cbv[nt] = *(const float4*)(cb + nt*16);

    float bias[3];
    #pragma unroll
    for (int nt = 0; nt < 3; ++nt){
      int ct = w*3 + nt, s = ct >> 2;
      bias[nt] = bqkv[s*384 + h*64 + (ct & 3)*16 + l15];
      if (s == 0) bias[nt] *= SCALE;
    }

    // ---- QKV GEMM: A from LDS + B from L2, both 2-deep register dbuf ----
    const unsigned short* Bb = wqf + ((long)h*12 + w*3)*12*512;
    short8 aA[2][4], bB[2][3];
    #pragma unroll
    for (int mt = 0; mt < 4; ++mt)
      aA[0][mt] = *(const short8*)(smem + mt*1024 + l*16);
    #pragma unroll
    for (int nt = 0; nt < 3; ++nt)
      bB[0][nt] = *(const short8*)(Bb + (nt*12)*512 + l*8);
    f32x4 acc[4][3];
    #pragma unroll
    for (int mt = 0; mt < 4; ++mt)
      #pragma unroll
      for (int nt = 0; nt < 3; ++nt)
        #pragma unroll
        for (int j = 0; j < 4; ++j) acc[mt][nt][j] = bias[nt];

    #pragma unroll
    for (int kt = 0; kt < 12; ++kt){
      const int cur = kt & 1, nxt = cur ^ 1;
      if (kt < 11){
        #pragma unroll
        for (int nt = 0; nt < 3; ++nt)
          bB[nxt][nt] = *(const short8*)(Bb + (nt*12 + kt+1)*512 + l*8);
        #pragma unroll
        for (int mt = 0; mt < 4; ++mt)
          aA[nxt][mt] = *(const short8*)(smem + ((kt+1)*4 + mt)*1024 + l*16);
      }
      __builtin_amdgcn_sched_barrier(0);   // kt+1 loads stay above kt's MFMAs
      __builtin_amdgcn_s_setprio(1);
      #pragma unroll
      for (int nt = 0; nt < 3; ++nt){
        #pragma unroll
        for (int mt = 0; mt < 4; ++mt)
          acc[mt][nt] = __builtin_amdgcn_mfma_f32_16x16x32_bf16(aA[cur][mt], bB[cur][nt], acc[mt][nt], 0, 0, 0);
      }
      __builtin_amdgcn_s_setprio(0);
    }

    // ---- scatter q / k (b16) and vt (transposed, b64) to LDS ----
    #pragma unroll
    for (int nt = 0; nt < 3; ++nt){
      int ct = w*3 + nt, s = ct >> 2, d16 = (ct & 3) * 16;
      if (s == 2){
        #pragma unroll
        for (int mt = 0; mt < 4; ++mt){
          uint2 p = pk4(acc[mt][nt][0], acc[mt][nt][1], acc[mt][nt][2], acc[mt][nt][3]);
          *(uint2*)(smem + a_vt(d16 + l15, mt*16 + lg*4)) = p;
        }
      } else {
        #pragma unroll
        for (int mt = 0; mt < 4; ++mt){
          #pragma unroll
          for (int j = 0; j < 4; ++j){
            int row = mt*16 + lg*4 + j;
            int addr = (s == 0) ? a_q(row, d16 + l15) : a_k(row, d16 + l15);
            *(unsigned short*)(smem + addr) = cvt1(acc[mt][nt][j]);
          }
        }
      }
    }
    __syncthreads();   // (a) q/k/vt ready

    // ---- S^T = K * Q^T : lane owns q-row w*16+l15, holds 64 k-scores ----
    short8 bq[2];
    #pragma unroll
    for (int ks = 0; ks < 2; ++ks)
      bq[ks] = *(const short8*)(smem + a_q(w*16 + l15, ks*32 + lg*8));
    f32x4 st[4] = {};
    __builtin_amdgcn_s_setprio(1);
    #pragma unroll
    for (int ks = 0; ks < 2; ++ks){
      #pragma unroll
      for (int nt = 0; nt < 4; ++nt){
        short8 ak = *(const short8*)(smem + a_k(nt*16 + l15, ks*32 + lg*8));
        st[nt] = __builtin_amdgcn_mfma_f32_16x16x32_bf16(ak, bq[ks], st[nt], 0, 0, 0);
      }
    }
    __builtin_amdgcn_s_setprio(0);
    // + (rpb+mask); softmax over k: in-lane 16 + cross-lane ^16,^32
    #pragma unroll
    for (int nt = 0; nt < 4; ++nt){
      st[nt][0] += cbv[nt].x; st[nt][1] += cbv[nt].y;
      st[nt][2] += cbv[nt].z; st[nt][3] += cbv[nt].w;
    }
    float mx;
    {
      float m0 = fmaxf(fmaxf(st[0][0], st[0][1]), fmaxf(st[0][2], st[0][3]));
      float m1 = fmaxf(fmaxf(st[1][0], st[1][1]), fmaxf(st[1][2], st[1][3]));
      float m2 = fmaxf(fmaxf(st[2][0], st[2][1]), fmaxf(st[2][2], st[2][3]));
      float m3 = fmaxf(fmaxf(st[3][0], st[3][1]), fmaxf(st[3][2], st[3][3]));
      mx = fmaxf(fmaxf(m0, m1), fmaxf(m2, m3));
    }
    mx = fmaxf(mx, __shfl_xor(mx, 16));
    mx = fmaxf(mx, __shfl_xor(mx, 32));
    float ssum = 0.f;
    #pragma unroll
    for (int nt = 0; nt < 4; ++nt){
      #pragma unroll
      for (int j = 0; j < 4; ++j){
        float e = __expf(st[nt][j] - mx);
        st[nt][j] = e; ssum += e;
      }
    }
    ssum += __shfl_xor(ssum, 16);
    ssum += __shfl_xor(ssum, 32);
    const float inv = 1.0f / ssum;

    // pre-normalized P -> q buffer (own rows; b64 writes)
    #pragma unroll
    for (int nt = 0; nt < 4; ++nt){
      uint2 p = pk4(st[nt][0]*inv, st[nt][1]*inv, st[nt][2]*inv, st[nt][3]*inv);
      *(uint2*)(smem + a_q(w*16 + l15, nt*16 + lg*4)) = p;
    }

    // ---- O = Pn * V ----
    short8 ap[2];
    #pragma unroll
    for (int ks = 0; ks < 2; ++ks)
      ap[ks] = *(const short8*)(smem + a_q(w*16 + l15, ks*32 + lg*8));
    f32x4 oacc[4] = {};
    __builtin_amdgcn_s_setprio(1);
    #pragma unroll
    for (int ks = 0; ks < 2; ++ks){
      #pragma unroll
      for (int nt = 0; nt < 4; ++nt){
        short8 bv = *(const short8*)(smem + a_vt(nt*16 + l15, ks*32 + lg*8));
        oacc[nt] = __builtin_amdgcn_mfma_f32_16x16x32_bf16(ap[ks], bv, oacc[nt], 0, 0, 0);
      }
    }
    __builtin_amdgcn_s_setprio(0);
    // O[r=w*16+lg*4+j][c=nt*16+l15] -> obuf in A-frag layout (scalar bf16 writes)
    #pragma unroll
    for (int nt = 0; nt < 4; ++nt){
      int frag  = (nt >> 1)*4 + w;
      int chunk0 = (lg*4) + ((nt & 1)*2 + (l15 >> 3))*16;
      #pragma unroll
      for (int j = 0; j < 4; ++j){
        int addr = OBUF + frag*1024 + (chunk0 + j)*16 + (l15 & 7)*2;
        *(unsigned short*)(smem + addr) = cvt1(oacc[nt][j]);
      }
    }
    __syncthreads();   // (b) obuf ready

    // ---- proj partial GEMM: pacc += O_head @ wp[:, h*64:(h+1)*64]^T ----
    #pragma unroll
    for (int ks = 0; ks < 2; ++ks){
      short8 aO[4];
      #pragma unroll
      for (int mt = 0; mt < 4; ++mt)
        aO[mt] = *(const short8*)(smem + OBUF + (ks*4 + mt)*1024 + l*16);
      __builtin_amdgcn_s_setprio(1);
      #pragma unroll
      for (int nt = 0; nt < 3; ++nt){
        short8 bb = *(const short8*)(wpf + ((long)(w*3 + nt)*12 + h*2 + ks)*512 + l*8);
        #pragma unroll
        for (int mt = 0; mt < 4; ++mt)
          pacc[mt][nt] = __builtin_amdgcn_mfma_f32_16x16x32_bf16(aO[mt], bb, pacc[mt][nt], 0, 0, 0);
      }
      __builtin_amdgcn_s_setprio(0);
    }
  }

  // ---- epilogue: store f32 rows < 49 (bias already in pacc) ----
  #pragma unroll
  for (int mt = 0; mt < 4; ++mt){
    #pragma unroll
    for (int j = 0; j < 4; ++j){
      int row = mt*16 + lg*4 + j;
      if (row < 49){
        float* o = out + ((long)win*49 + row)*192;
        #pragma unroll
        for (int nt = 0; nt < 3; ++nt)
          o[np[nt]] = pacc[mt][nt][j];
      }
    }
  }
}

// ================= fallback (round-2 fused kernel, if ws too small) =================
#define FB_WQ_ELEMS (1152*384)
#define FB_WP_ELEMS (192*384)
#define FB_WP_OFF   (FB_WQ_ELEMS*2)
#define FB_COMB_OFF (FB_WP_OFF + FB_WP_ELEMS*2)

__global__ void prep_weights_fb(const float* __restrict__ wq_f, const float* __restrict__ wp_f,
                                unsigned short* __restrict__ wq, unsigned short* __restrict__ wp){
  int gid = blockIdx.x * 256 + threadIdx.x;
  if (gid < FB_WQ_ELEMS) wq[gid] = f2bf(wq_f[gid]);
  else { int g = gid - FB_WQ_ELEMS; if (g < FB_WP_ELEMS) wp[g] = f2bf(wp_f[g]); }
}
__device__ __forceinline__ int fb_xy(int r, int c){ return 0      + swz(r, r*768 + c*2); }
__device__ __forceinline__ int fb_q (int r, int c){ return 49152  + swz(r, r*128 + c*2); }
__device__ __forceinline__ int fb_k (int r, int c){ return 57344  + swz(r, r*128 + c*2); }
__device__ __forceinline__ int fb_vt(int r, int c){ return 65536  + swz(r, r*128 + c*2); }
__device__ __forceinline__ int fb_p (int r, int c){ return 73728  + swz(r, r*128 + c*2); }

__global__ __launch_bounds__(256, 2)
void fused_attn_fb(const float* __restrict__ x, const float* __restrict__ y,
                   const float* __restrict__ bqkv, const float* __restrict__ bproj,
                   const unsigned short* __restrict__ wq, const unsigned short* __restrict__ wp,
                   const float* __restrict__ comb, float* __restrict__ out){
  __shared__ __align__(16) unsigned char smem[81920];
  const int b = blockIdx.x, tid = threadIdx.x;
  const int w = tid>>6, l = tid&63, l15 = l&15, lg = l>>4;
  {
    const float4* x4 = (const float4*)x + b * 2352;
    const float4* y4 = (const float4*)y + b * 2352;
    for (int idx = tid; idx < 2352; idx += 256){
      int r = idx / 48, c4 = (idx % 48) * 4;
      float4 vx = x4[idx], vy = y4[idx];
      *(unsigned long long*)(smem + fb_xy(r, c4))       = pack4(vx);
      *(unsigned long long*)(smem + fb_xy(r, 192 + c4)) = pack4(vy);
    }
    for (int idx = tid; idx < 1440; idx += 256){
      int r = 49 + idx / 96, c4 = (idx % 96) * 4;
      *(unsigned long long*)(smem + fb_xy(r, c4)) = 0ull;
    }
  }
  __syncthreads();
  const float* cbB = comb + (long)(b & 63) * (6 * 4096);
  f32x4 pacc[4][3] = {};
  int np[3]; float bp[3];
  #pragma unroll
  for (int nt = 0; nt < 3; ++nt){ np[nt] = w*48 + nt*16 + l15; bp[nt] = bproj[np[nt]]; }
  #pragma unroll 1
  for (int h = 0; h < 6; ++h){
    f32x4 acc[4][3] = {};
    int wrow[3]; float bias[3];
    #pragma unroll
    for (int nt = 0; nt < 3; ++nt){
      int n = np[nt];
      wrow[nt] = (n >> 6) * 384 + h * 64 + (n & 63);
      bias[nt] = bqkv[wrow[nt]];
    }
    #pragma unroll 4
    for (int kt = 0; kt < 12; ++kt){
      int k0 = kt * 32;
      short8 a[4];
      #pragma unroll
      for (int mt = 0; mt < 4; ++mt)
        a[mt] = *(const short8*)(smem + fb_xy(mt*16 + l15, k0 + lg*8));
      #pragma unroll
      for (int nt = 0; nt < 3; ++nt){
        short8 bb = *(const short8*)(wq + (long)wrow[nt]*384 + k0 + lg*8);
        #pragma unroll
        for (int mt = 0; mt < 4; ++mt)
          acc[mt][nt] = __builtin_amdgcn_mfma_f32_16x16x32_bf16(a[mt], bb, acc[mt][nt], 0, 0, 0);
      }
    }
    #pragma unroll
    for (int nt = 0; nt < 3; ++nt){
      int n = np[nt], s = n >> 6, d = n & 63;
      #pragma unroll
      for (int mt = 0; mt < 4; ++mt){
        #pragma unroll
        for (int j = 0; j < 4; ++j){
          int row = mt*16 + lg*4 + j;
          float v = acc[mt][nt][j] + bias[nt];
          if (s == 0) v *= SCALE;
          int addr = (s==0) ? fb_q(row,d) : (s==1) ? fb_k(row,d) : fb_vt(d,row);
          *(unsigned short*)(smem + addr) = f2bf(v);
        }
      }
    }
    __syncthreads();
    short8 aq[2];
    #pragma unroll
    for (int ks = 0; ks < 2; ++ks)
      aq[ks] = *(const short8*)(smem + fb_q(w*16 + l15, ks*32 + lg*8));
    f32x4 sacc[4] = {};
    #pragma unroll
    for (int ks = 0; ks < 2; ++ks)
      #pragma unroll
      for (int nt = 0; nt < 4; ++nt){
        short8 bk = *(const short8*)(smem + fb_k(nt*16 + l15, ks*32 + lg*8));
        sacc[nt] = __builtin_amdgcn_mfma_f32_16x16x32_bf16(aq[ks], bk, sacc[nt], 0, 0, 0);
      }
    const float* cb = cbB + h * 4096;
    float rs[4];
    #pragma unroll
    for (int j = 0; j < 4; ++j){
      int r = w*16 + lg*4 + j;
      #pragma unroll
      for (int nt = 0; nt < 4; ++nt) sacc[nt][j] += cb[r*64 + nt*16 + l15];
      float m = fmaxf(fmaxf(sacc[0][j], sacc[1][j]), fmaxf(sacc[2][j], sacc[3][j]));
      #pragma unroll
      for (int dlt = 1; dlt < 16; dlt <<= 1) m = fmaxf(m, __shfl_xor(m, dlt));
      float ssum = 0.f;
      #pragma unroll
      for (int nt = 0; nt < 4; ++nt){
        float e = __expf(sacc[nt][j] - m);
        sacc[nt][j] = e; ssum += e;
      }
      #pragma unroll
      for (int dlt = 1; dlt < 16; dlt <<= 1) ssum += __shfl_xor(ssum, dlt);
      rs[j] = ssum;
      #pragma unroll
      for (int nt = 0; nt < 4; ++nt)
        *(unsigned short*)(smem + fb_p(r, nt*16 + l15)) = f2bf(sacc[nt][j]);
    }
    short8 ap[2];
    #pragma unroll
    for (int ks = 0; ks < 2; ++ks)
      ap[ks] = *(const short8*)(smem + fb_p(w*16 + l15, ks*32 + lg*8));
    f32x4 oacc[4] = {};
    #pragma unroll
    for (int ks = 0; ks < 2; ++ks)
      #pragma unroll
      for (int nt = 0; nt < 4; ++nt){
        short8 bv = *(const short8*)(smem + fb_vt(nt*16 + l15, ks*32 + lg*8));
        oacc[nt] = __builtin_amdgcn_mfma_f32_16x16x32_bf16(ap[ks], bv, oacc[nt], 0, 0, 0);
      }
    float inv[4];
    #pragma unroll
    for (int j = 0; j < 4; ++j) inv[j] = 1.0f / rs[j];
    #pragma unroll
    for (int nt = 0; nt < 4; ++nt)
      #pragma unroll
      for (int j = 0; j < 4; ++j){
        int row = w*16 + lg*4 + j;
        *(unsigned short*)(smem + fb_p(row, nt*16 + l15)) = f2bf(oacc[nt][j] * inv[j]);
      }
    __syncthreads();
    #pragma unroll
    for (int ks = 0; ks < 2; ++ks){
      short8 ao8[4];
      #pragma unroll
      for (int mt = 0; mt < 4; ++mt)
        ao8[mt] = *(const short8*)(smem + fb_p(mt*16 + l15, ks*32 + lg*8));
      #pragma unroll
      for (int nt = 0; nt < 3; ++nt){
        short8 bb = *(const short8*)(wp + (long)np[nt]*384 + h*64 + ks*32 + lg*8);
        #pragma unroll
        for (int mt = 0; mt < 4; ++mt)
          pacc[mt][nt] = __builtin_amdgcn_mfma_f32_16x16x32_bf16(ao8[mt], bb, pacc[mt][nt], 0, 0, 0);
      }
    }
  }
  #pragma unroll
  for (int mt = 0; mt < 4; ++mt)
    #pragma unroll
    for (int j = 0; j < 4; ++j){
      int row = mt*16 + lg*4 + j;
      if (row < 49){
        float* o = out + ((long)b*49 + row)*192;
        #pragma unroll
        for (int nt = 0; nt < 3; ++nt)
          o[np[nt]] = pacc[mt][nt][j] + bp[nt];
      }
    }
}

// ---------------- launch ----------------
extern "C" void kernel_launch(void* const* d_in, const int* in_sizes, int n_in,
                              void* d_out, int out_size, void* d_ws, size_t ws_size,
                              hipStream_t stream){
  (void)in_sizes; (void)n_in; (void)out_size;
  const float* x     = (const float*)d_in[0];
  const float* y     = (const float*)d_in[1];
  const float* mask  = (const float*)d_in[2];
  const float* wq_f  = (const float*)d_in[3];
  const float* bqkv  = (const float*)d_in[4];
  const float* wp_f  = (const float*)d_in[5];
  const float* bproj = (const float*)d_in[6];
  const float* btab  = (const float*)d_in[7];
  float* out = (float*)d_out;

  if (ws_size >= WS_NEED){
    unsigned short* wqf = (unsigned short*)((char*)d_ws + WQF_OFF);
    unsigned short* wpf = (unsigned short*)((char*)d_ws + WPF_OFF);
    float*          cmb = (float*)((char*)d_ws + COMB_OFF);
    hipLaunchKernelGGL(k0_wfrag,  dim3(252),  dim3(256), 0, stream, wq_f, wp_f, wqf, wpf);
    hipLaunchKernelGGL(prep_comb, dim3(6144), dim3(256), 0, stream, mask, btab, cmb);
    hipLaunchKernelGGL(k_fused,   dim3(2048), dim3(256), 0, stream,
                       x, y, wqf, wpf, bqkv, bproj, cmb, out);
  } else {
    unsigned short* wq  = (unsigned short*)d_ws;
    unsigned short* wp  = (unsigned short*)((char*)d_ws + FB_WP_OFF);
    float*          cmb = (float*)((char*)d_ws + FB_COMB_OFF);
    hipLaunchKernelGGL(prep_weights_fb, dim3(2016), dim3(256), 0, stream, wq_f, wp_f, wq, wp);
    hipLaunchKernelGGL(prep_comb,       dim3(6144), dim3(256), 0, stream, mask, btab, cmb);
    hipLaunchKernelGGL(fused_attn_fb,   dim3(2048), dim3(256), 0, stream,
                       x, y, bqkv, bproj, wq, wp, cmb, out);
  }
}

// Round 11
// 220.582 us; speedup vs baseline: 1.4174x; 1.4174x over previous
//
#include <hip/hip_runtime.h>
#include <hip/hip_bf16.h>

// WindowAttention, round 11 = round-8 champion + two isolated fixes:
//  (a) dest-linear A-frag staging (R9 FIX1: conflicts 8.65M->3.1M measured;
//      R9's regression was the dbuf spill, not this).
//  (b) NO sched_barrier(0) in the QKV K-loop: R8 pinned kt's A-reads directly
//      against kt's MFMAs, blocking cross-iteration pipelining (~120cy stall
//      per kt). Compiler's counted-lgkmcnt scheduling handles the unrolled
//      loop (m97/m141 evidence). B-dbuf + setprio kept. launch_bounds(256,2)
//      kept (R10 proved bound=1 halves co-residency: 2 blocks/CU -> 1).
// Register-dbuf for A is permanently abandoned (R5/R9/R10: unaffordable).

typedef __attribute__((ext_vector_type(8))) short short8;
typedef __attribute__((ext_vector_type(4))) float f32x4;

#define SCALE 0.17677669529663687f  // (192/6)^-0.5

// ---------------- ws layout ----------------
#define WQF_OFF    0ul
#define WQF_BYTES  (864ul*1024)                  // 6h*12ct*12kt frags
#define WPF_OFF    (WQF_OFF + WQF_BYTES)
#define WPF_BYTES  (144ul*1024)                  // 12ct*12kt frags
#define COMB_OFF   (WPF_OFF + WPF_BYTES)
#define COMB_BYTES (64ul*6*4096*4)
#define WS_NEED    (COMB_OFF + COMB_BYTES)       // ~7.3 MB

__device__ __forceinline__ unsigned short f2bf(float f){
  unsigned u = __builtin_bit_cast(unsigned, f);
  u = u + 0x7fffu + ((u >> 16) & 1u);            // round-to-nearest-even
  return (unsigned short)(u >> 16);
}
__device__ __forceinline__ unsigned long long pack4(float4 v){
  return (unsigned long long)f2bf(v.x) | ((unsigned long long)f2bf(v.y) << 16)
       | ((unsigned long long)f2bf(v.z) << 32) | ((unsigned long long)f2bf(v.w) << 48);
}

// HW bf16 converts (RNE, same as f2bf).
__device__ __forceinline__ unsigned short cvt1(float x){
  unsigned r;
  asm("v_cvt_pk_bf16_f32 %0, %1, %1" : "=v"(r) : "v"(x));
  return (unsigned short)r;
}
__device__ __forceinline__ uint2 pk4(float a, float b, float c, float d){
  unsigned lo, hi;
  asm("v_cvt_pk_bf16_f32 %0, %1, %2" : "=v"(lo) : "v"(a), "v"(b));
  asm("v_cvt_pk_bf16_f32 %0, %1, %2" : "=v"(hi) : "v"(c), "v"(d));
  return make_uint2(lo, hi);
}

// ---------------- prep: weights -> fragments ----------------
__global__ void k0_wfrag(const float* __restrict__ wq_f, const float* __restrict__ wp_f,
                         unsigned short* __restrict__ wqf, unsigned short* __restrict__ wpf){
  int t = blockIdx.x*256 + threadIdx.x;          // exactly 1008*64
  int fragidx = t >> 6, l = t & 63;
  const float* src; unsigned short* dst;
  float sc = 1.0f;
  if (fragidx < 864){
    int h = fragidx/144, rem = fragidx - h*144;
    int ct = rem/12, kt = rem - ct*12;
    int row = (ct>>2)*384 + h*64 + (ct&3)*16 + (l&15);
    src = wq_f + (long)row*384 + kt*32 + (l>>4)*8;
    dst = wqf + (long)fragidx*512 + l*8;
    if (ct < 4) sc = SCALE;                      // fold softmax scale into q-weights
  } else {
    int fid = fragidx - 864;
    int ct = fid/12, kt = fid - ct*12;
    int row = ct*16 + (l&15);
    src = wp_f + (long)row*384 + kt*32 + (l>>4)*8;
    dst = wpf + (long)fid*512 + l*8;
  }
  short8 v;
  #pragma unroll
  for (int e = 0; e < 8; ++e) v[e] = (short)f2bf(src[e] * sc);
  *(short8*)dst = v;
}

// comb[w][h][i][j] = rpb[h][i][j] + mask[w][i][j]; pad cols j>=49 -> -1e30
__global__ void prep_comb(const float* __restrict__ mask, const float* __restrict__ btab,
                          float* __restrict__ comb){
  int idx = blockIdx.x * 256 + threadIdx.x;      // < 64*6*4096
  int j = idx & 63, i = (idx >> 6) & 63, rest = idx >> 12;
  int h = rest % 6, w = rest / 6;
  float v;
  if (i < 49 && j < 49){
    int di = i / 7 - j / 7 + 6;
    int dj = i % 7 - j % 7 + 6;
    v = btab[(di * 13 + dj) * 6 + h] + mask[(w * 49 + i) * 49 + j];
  } else {
    v = (j >= 49) ? -1e30f : 0.0f;
  }
  comb[idx] = v;
}

// ---------------- fused kernel ----------------
// LDS 80 KiB: A-frags @0 (48K, lives whole kernel), q@49152, k@57344,
// vt@65536 (XOR-swizzled [64][64] bf16), obuf @73728 (8K, O in frag layout).
__device__ __forceinline__ int swz(int r, int b){ return b ^ ((r & 7) << 4); }
__device__ __forceinline__ int a_q (int r, int c){ return 49152 + swz(r, r*128 + c*2); }
__device__ __forceinline__ int a_k (int r, int c){ return 57344 + swz(r, r*128 + c*2); }
__device__ __forceinline__ int a_vt(int r, int c){ return 65536 + swz(r, r*128 + c*2); }
#define OBUF 73728

__global__ __launch_bounds__(256, 2)
void k_fused(const float* __restrict__ x, const float* __restrict__ y,
             const unsigned short* __restrict__ wqf, const unsigned short* __restrict__ wpf,
             const float* __restrict__ bqkv, const float* __restrict__ bproj,
             const float* __restrict__ comb, float* __restrict__ out){
  __shared__ __align__(16) unsigned char smem[81920];
  const int win = blockIdx.x;
  const int tid = threadIdx.x, w = tid>>6, l = tid&63, l15 = l&15, lg = l>>4;

  // ---- stage concat(x,y) -> A-frags in LDS, DEST-LINEAR writes (R9 FIX1) ----
  // frag f; lane l supplies A[row=mt*16+(l&15)][col=kt*32+(l>>4)*8 ..+8] and
  // writes slot l (16 B) of the frag -> zero LDS write conflicts.
  #pragma unroll
  for (int i = 0; i < 12; ++i){
    int f  = w*12 + i;                     // wave w stages frags w*12..w*12+11
    int kt = f >> 2, mt = f & 3;
    int row = mt*16 + l15;
    int c   = kt*32 + lg*8;                // wave-uniform branch below
    uint4 vv = make_uint4(0,0,0,0);
    if (row < 49){
      const float* src = (c < 192) ? (x + ((long)win*49 + row)*192 + c)
                                   : (y + ((long)win*49 + row)*192 + (c - 192));
      float4 f0 = *(const float4*)src, f1 = *(const float4*)(src + 4);
      uint2 lo = pk4(f0.x, f0.y, f0.z, f0.w);
      uint2 hi = pk4(f1.x, f1.y, f1.z, f1.w);
      vv = make_uint4(lo.x, lo.y, hi.x, hi.y);
    }
    *(uint4*)(smem + f*1024 + l*16) = vv;
  }

  // proj accumulators: bias in C-init, live across the head loop
  int np[3];
  f32x4 pacc[4][3];
  #pragma unroll
  for (int nt = 0; nt < 3; ++nt){
    np[nt] = w*48 + nt*16 + l15;
    float bv = bproj[np[nt]];
    #pragma unroll
    for (int mt = 0; mt < 4; ++mt)
      #pragma unroll
      for (int j = 0; j < 4; ++j) pacc[mt][nt][j] = bv;
  }

  __syncthreads();   // A-panel staged

  #pragma unroll 1
  for (int h = 0; h < 6; ++h){
    // comb tile prefetch (consumed post-QK^T; hides under the GEMM)
    const float* cb = comb + ((long)((win & 63)*6 + h))*4096 + (w*16 + l15)*64 + lg*4;
    float4 cbv[4];
    #pragma unroll
    for (int nt = 0; nt < 4; ++nt) cbv[nt] = *(const float4*)(cb + nt*16);

    float bias[3];
    #pragma unroll
    for (int nt = 0; nt < 3; ++nt){
      int ct = w*3 + nt, s = ct >> 2;
      bias[nt] = bqkv[s*384 + h*64 + (ct & 3)*16 + l15];
      if (s == 0) bias[nt] *= SCALE;
    }

    // ---- QKV GEMM: A from LDS, B dbuf from L2. NO sched_barrier — let the
    //      compiler software-pipeline the unrolled loop (counted lgkmcnt). ----
    const unsigned short* Bb = wqf + ((long)h*12 + w*3)*12*512;
    short8 bB[2][3];
    #pragma unroll
    for (int nt = 0; nt < 3; ++nt)
      bB[0][nt] = *(const short8*)(Bb + (nt*12)*512 + l*8);
    f32x4 acc[4][3];
    #pragma unroll
    for (int mt = 0; mt < 4; ++mt)
      #pragma unroll
      for (int nt = 0; nt < 3; ++nt)
        #pragma unroll
        for (int j = 0; j < 4; ++j) acc[mt][nt][j] = bias[nt];

    #pragma unroll
    for (int kt = 0; kt < 12; ++kt){
      const int cur = kt & 1, nxt = cur ^ 1;
      if (kt < 11){
        #pragma unroll
        for (int nt = 0; nt < 3; ++nt)
          bB[nxt][nt] = *(const short8*)(Bb + (nt*12 + kt+1)*512 + l*8);
      }
      short8 aA[4];
      #pragma unroll
      for (int mt = 0; mt < 4; ++mt)
        aA[mt] = *(const short8*)(smem + (kt*4 + mt)*1024 + l*16);
      __builtin_amdgcn_s_setprio(1);
      #pragma unroll
      for (int nt = 0; nt < 3; ++nt){
        #pragma unroll
        for (int mt = 0; mt < 4; ++mt)
          acc[mt][nt] = __builtin_amdgcn_mfma_f32_16x16x32_bf16(aA[mt], bB[cur][nt], acc[mt][nt], 0, 0, 0);
      }
      __builtin_amdgcn_s_setprio(0);
    }

    // ---- scatter q / k (b16) and vt (transposed, b64) to LDS ----
    #pragma unroll
    for (int nt = 0; nt < 3; ++nt){
      int ct = w*3 + nt, s = ct >> 2, d16 = (ct & 3) * 16;
      if (s == 2){
        #pragma unroll
        for (int mt = 0; mt < 4; ++mt){
          uint2 p = pk4(acc[mt][nt][0], acc[mt][nt][1], acc[mt][nt][2], acc[mt][nt][3]);
          *(uint2*)(smem + a_vt(d16 + l15, mt*16 + lg*4)) = p;
        }
      } else {
        #pragma unroll
        for (int mt = 0; mt < 4; ++mt){
          #pragma unroll
          for (int j = 0; j < 4; ++j){
            int row = mt*16 + lg*4 + j;
            int addr = (s == 0) ? a_q(row, d16 + l15) : a_k(row, d16 + l15);
            *(unsigned short*)(smem + addr) = cvt1(acc[mt][nt][j]);
          }
        }
      }
    }
    __syncthreads();   // (a) q/k/vt ready

    // ---- S^T = K * Q^T : lane owns q-row w*16+l15, holds 64 k-scores ----
    short8 bq[2];
    #pragma unroll
    for (int ks = 0; ks < 2; ++ks)
      bq[ks] = *(const short8*)(smem + a_q(w*16 + l15, ks*32 + lg*8));
    f32x4 st[4] = {};
    __builtin_amdgcn_s_setprio(1);
    #pragma unroll
    for (int ks = 0; ks < 2; ++ks){
      #pragma unroll
      for (int nt = 0; nt < 4; ++nt){
        short8 ak = *(const short8*)(smem + a_k(nt*16 + l15, ks*32 + lg*8));
        st[nt] = __builtin_amdgcn_mfma_f32_16x16x32_bf16(ak, bq[ks], st[nt], 0, 0, 0);
      }
    }
    __builtin_amdgcn_s_setprio(0);
    // + (rpb+mask); softmax over k: in-lane 16 + cross-lane ^16,^32
    #pragma unroll
    for (int nt = 0; nt < 4; ++nt){
      st[nt][0] += cbv[nt].x; st[nt][1] += cbv[nt].y;
      st[nt][2] += cbv[nt].z; st[nt][3] += cbv[nt].w;
    }
    float mx;
    {
      float m0 = fmaxf(fmaxf(st[0][0], st[0][1]), fmaxf(st[0][2], st[0][3]));
      float m1 = fmaxf(fmaxf(st[1][0], st[1][1]), fmaxf(st[1][2], st[1][3]));
      float m2 = fmaxf(fmaxf(st[2][0], st[2][1]), fmaxf(st[2][2], st[2][3]));
      float m3 = fmaxf(fmaxf(st[3][0], st[3][1]), fmaxf(st[3][2], st[3][3]));
      mx = fmaxf(fmaxf(m0, m1), fmaxf(m2, m3));
    }
    mx = fmaxf(mx, __shfl_xor(mx, 16));
    mx = fmaxf(mx, __shfl_xor(mx, 32));
    float ssum = 0.f;
    #pragma unroll
    for (int nt = 0; nt < 4; ++nt){
      #pragma unroll
      for (int j = 0; j < 4; ++j){
        float e = __expf(st[nt][j] - mx);
        st[nt][j] = e; ssum += e;
      }
    }
    ssum += __shfl_xor(ssum, 16);
    ssum += __shfl_xor(ssum, 32);
    const float inv = 1.0f / ssum;

    // pre-normalized P -> q buffer (own rows; b64 writes)
    #pragma unroll
    for (int nt = 0; nt < 4; ++nt){
      uint2 p = pk4(st[nt][0]*inv, st[nt][1]*inv, st[nt][2]*inv, st[nt][3]*inv);
      *(uint2*)(smem + a_q(w*16 + l15, nt*16 + lg*4)) = p;
    }

    // ---- O = Pn * V ----
    short8 ap[2];
    #pragma unroll
    for (int ks = 0; ks < 2; ++ks)
      ap[ks] = *(const short8*)(smem + a_q(w*16 + l15, ks*32 + lg*8));
    f32x4 oacc[4] = {};
    __builtin_amdgcn_s_setprio(1);
    #pragma unroll
    for (int ks = 0; ks < 2; ++ks){
      #pragma unroll
      for (int nt = 0; nt < 4; ++nt){
        short8 bv = *(const short8*)(smem + a_vt(nt*16 + l15, ks*32 + lg*8));
        oacc[nt] = __builtin_amdgcn_mfma_f32_16x16x32_bf16(ap[ks], bv, oacc[nt], 0, 0, 0);
      }
    }
    __builtin_amdgcn_s_setprio(0);
    // O[r=w*16+lg*4+j][c=nt*16+l15] -> obuf in A-frag layout (scalar bf16 writes)
    #pragma unroll
    for (int nt = 0; nt < 4; ++nt){
      int frag  = (nt >> 1)*4 + w;
      int chunk0 = (lg*4) + ((nt & 1)*2 + (l15 >> 3))*16;
      #pragma unroll
      for (int j = 0; j < 4; ++j){
        int addr = OBUF + frag*1024 + (chunk0 + j)*16 + (l15 & 7)*2;
        *(unsigned short*)(smem + addr) = cvt1(oacc[nt][j]);
      }
    }
    __syncthreads();   // (b) obuf ready

    // ---- proj partial GEMM: pacc += O_head @ wp[:, h*64:(h+1)*64]^T ----
    #pragma unroll
    for (int ks = 0; ks < 2; ++ks){
      short8 aO[4];
      #pragma unroll
      for (int mt = 0; mt < 4; ++mt)
        aO[mt] = *(const short8*)(smem + OBUF + (ks*4 + mt)*1024 + l*16);
      __builtin_amdgcn_s_setprio(1);
      #pragma unroll
      for (int nt = 0; nt < 3; ++nt){
        short8 bb = *(const short8*)(wpf + ((long)(w*3 + nt)*12 + h*2 + ks)*512 + l*8);
        #pragma unroll
        for (int mt = 0; mt < 4; ++mt)
          pacc[mt][nt] = __builtin_amdgcn_mfma_f32_16x16x32_bf16(aO[mt], bb, pacc[mt][nt], 0, 0, 0);
      }
      __builtin_amdgcn_s_setprio(0);
    }
  }

  // ---- epilogue: store f32 rows < 49 (bias already in pacc) ----
  #pragma unroll
  for (int mt = 0; mt < 4; ++mt){
    #pragma unroll
    for (int j = 0; j < 4; ++j){
      int row = mt*16 + lg*4 + j;
      if (row < 49){
        float* o = out + ((long)win*49 + row)*192;
        #pragma unroll
        for (int nt = 0; nt < 3; ++nt)
          o[np[nt]] = pacc[mt][nt][j];
      }
    }
  }
}

// ================= fallback (round-2 fused kernel, if ws too small) =================
#define FB_WQ_ELEMS (1152*384)
#define FB_WP_ELEMS (192*384)
#define FB_WP_OFF   (FB_WQ_ELEMS*2)
#define FB_COMB_OFF (FB_WP_OFF + FB_WP_ELEMS*2)

__global__ void prep_weights_fb(const float* __restrict__ wq_f, const float* __restrict__ wp_f,
                                unsigned short* __restrict__ wq, unsigned short* __restrict__ wp){
  int gid = blockIdx.x * 256 + threadIdx.x;
  if (gid < FB_WQ_ELEMS) wq[gid] = f2bf(wq_f[gid]);
  else { int g = gid - FB_WQ_ELEMS; if (g < FB_WP_ELEMS) wp[g] = f2bf(wp_f[g]); }
}
__device__ __forceinline__ int fb_xy(int r, int c){ return 0      + swz(r, r*768 + c*2); }
__device__ __forceinline__ int fb_q (int r, int c){ return 49152  + swz(r, r*128 + c*2); }
__device__ __forceinline__ int fb_k (int r, int c){ return 57344  + swz(r, r*128 + c*2); }
__device__ __forceinline__ int fb_vt(int r, int c){ return 65536  + swz(r, r*128 + c*2); }
__device__ __forceinline__ int fb_p (int r, int c){ return 73728  + swz(r, r*128 + c*2); }

__global__ __launch_bounds__(256, 2)
void fused_attn_fb(const float* __restrict__ x, const float* __restrict__ y,
                   const float* __restrict__ bqkv, const float* __restrict__ bproj,
                   const unsigned short* __restrict__ wq, const unsigned short* __restrict__ wp,
                   const float* __restrict__ comb, float* __restrict__ out){
  __shared__ __align__(16) unsigned char smem[81920];
  const int b = blockIdx.x, tid = threadIdx.x;
  const int w = tid>>6, l = tid&63, l15 = l&15, lg = l>>4;
  {
    const float4* x4 = (const float4*)x + b * 2352;
    const float4* y4 = (const float4*)y + b * 2352;
    for (int idx = tid; idx < 2352; idx += 256){
      int r = idx / 48, c4 = (idx % 48) * 4;
      float4 vx = x4[idx], vy = y4[idx];
      *(unsigned long long*)(smem + fb_xy(r, c4))       = pack4(vx);
      *(unsigned long long*)(smem + fb_xy(r, 192 + c4)) = pack4(vy);
    }
    for (int idx = tid; idx < 1440; idx += 256){
      int r = 49 + idx / 96, c4 = (idx % 96) * 4;
      *(unsigned long long*)(smem + fb_xy(r, c4)) = 0ull;
    }
  }
  __syncthreads();
  const float* cbB = comb + (long)(b & 63) * (6 * 4096);
  f32x4 pacc[4][3] = {};
  int np[3]; float bp[3];
  #pragma unroll
  for (int nt = 0; nt < 3; ++nt){ np[nt] = w*48 + nt*16 + l15; bp[nt] = bproj[np[nt]]; }
  #pragma unroll 1
  for (int h = 0; h < 6; ++h){
    f32x4 acc[4][3] = {};
    int wrow[3]; float bias[3];
    #pragma unroll
    for (int nt = 0; nt < 3; ++nt){
      int n = np[nt];
      wrow[nt] = (n >> 6) * 384 + h * 64 + (n & 63);
      bias[nt] = bqkv[wrow[nt]];
    }
    #pragma unroll 4
    for (int kt = 0; kt < 12; ++kt){
      int k0 = kt * 32;
      short8 a[4];
      #pragma unroll
      for (int mt = 0; mt < 4; ++mt)
        a[mt] = *(const short8*)(smem + fb_xy(mt*16 + l15, k0 + lg*8));
      #pragma unroll
      for (int nt = 0; nt < 3; ++nt){
        short8 bb = *(const short8*)(wq + (long)wrow[nt]*384 + k0 + lg*8);
        #pragma unroll
        for (int mt = 0; mt < 4; ++mt)
          acc[mt][nt] = __builtin_amdgcn_mfma_f32_16x16x32_bf16(a[mt], bb, acc[mt][nt], 0, 0, 0);
      }
    }
    #pragma unroll
    for (int nt = 0; nt < 3; ++nt){
      int n = np[nt], s = n >> 6, d = n & 63;
      #pragma unroll
      for (int mt = 0; mt < 4; ++mt){
        #pragma unroll
        for (int j = 0; j < 4; ++j){
          int row = mt*16 + lg*4 + j;
          float v = acc[mt][nt][j] + bias[nt];
          if (s == 0) v *= SCALE;
          int addr = (s==0) ? fb_q(row,d) : (s==1) ? fb_k(row,d) : fb_vt(d,row);
          *(unsigned short*)(smem + addr) = f2bf(v);
        }
      }
    }
    __syncthreads();
    short8 aq[2];
    #pragma unroll
    for (int ks = 0; ks < 2; ++ks)
      aq[ks] = *(const short8*)(smem + fb_q(w*16 + l15, ks*32 + lg*8));
    f32x4 sacc[4] = {};
    #pragma unroll
    for (int ks = 0; ks < 2; ++ks)
      #pragma unroll
      for (int nt = 0; nt < 4; ++nt){
        short8 bk = *(const short8*)(smem + fb_k(nt*16 + l15, ks*32 + lg*8));
        sacc[nt] = __builtin_amdgcn_mfma_f32_16x16x32_bf16(aq[ks], bk, sacc[nt], 0, 0, 0);
      }
    const float* cb = cbB + h * 4096;
    float rs[4];
    #pragma unroll
    for (int j = 0; j < 4; ++j){
      int r = w*16 + lg*4 + j;
      #pragma unroll
      for (int nt = 0; nt < 4; ++nt) sacc[nt][j] += cb[r*64 + nt*16 + l15];
      float m = fmaxf(fmaxf(sacc[0][j], sacc[1][j]), fmaxf(sacc[2][j], sacc[3][j]));
      #pragma unroll
      for (int dlt = 1; dlt < 16; dlt <<= 1) m = fmaxf(m, __shfl_xor(m, dlt));
      float ssum = 0.f;
      #pragma unroll
      for (int nt = 0; nt < 4; ++nt){
        float e = __expf(sacc[nt][j] - m);
        sacc[nt][j] = e; ssum += e;
      }
      #pragma unroll
      for (int dlt = 1; dlt < 16; dlt <<= 1) ssum += __shfl_xor(ssum, dlt);
      rs[j] = ssum;
      #pragma unroll
      for (int nt = 0; nt < 4; ++nt)
        *(unsigned short*)(smem + fb_p(r, nt*16 + l15)) = f2bf(sacc[nt][j]);
    }
    short8 ap[2];
    #pragma unroll
    for (int ks = 0; ks < 2; ++ks)
      ap[ks] = *(const short8*)(smem + fb_p(w*16 + l15, ks*32 + lg*8));
    f32x4 oacc[4] = {};
    #pragma unroll
    for (int ks = 0; ks < 2; ++ks)
      #pragma unroll
      for (int nt = 0; nt < 4; ++nt){
        short8 bv = *(const short8*)(smem + fb_vt(nt*16 + l15, ks*32 + lg*8));
        oacc[nt] = __builtin_amdgcn_mfma_f32_16x16x32_bf16(ap[ks], bv, oacc[nt], 0, 0, 0);
      }
    float inv[4];
    #pragma unroll
    for (int j = 0; j < 4; ++j) inv[j] = 1.0f / rs[j];
    #pragma unroll
    for (int nt = 0; nt < 4; ++nt)
      #pragma unroll
      for (int j = 0; j < 4; ++j){
        int row = w*16 + lg*4 + j;
        *(unsigned short*)(smem + fb_p(row, nt*16 + l15)) = f2bf(oacc[nt][j] * inv[j]);
      }
    __syncthreads();
    #pragma unroll
    for (int ks = 0; ks < 2; ++ks){
      short8 ao8[4];
      #pragma unroll
      for (int mt = 0; mt < 4; ++mt)
        ao8[mt] = *(const short8*)(smem + fb_p(mt*16 + l15, ks*32 + lg*8));
      #pragma unroll
      for (int nt = 0; nt < 3; ++nt){
        short8 bb = *(const short8*)(wp + (long)np[nt]*384 + h*64 + ks*32 + lg*8);
        #pragma unroll
        for (int mt = 0; mt < 4; ++mt)
          pacc[mt][nt] = __builtin_amdgcn_mfma_f32_16x16x32_bf16(ao8[mt], bb, pacc[mt][nt], 0, 0, 0);
      }
    }
  }
  #pragma unroll
  for (int mt = 0; mt < 4; ++mt)
    #pragma unroll
    for (int j = 0; j < 4; ++j){
      int row = mt*16 + lg*4 + j;
      if (row < 49){
        float* o = out + ((long)b*49 + row)*192;
        #pragma unroll
        for (int nt = 0; nt < 3; ++nt)
          o[np[nt]] = pacc[mt][nt][j] + bp[nt];
      }
    }
}

// ---------------- launch ----------------
extern "C" void kernel_launch(void* const* d_in, const int* in_sizes, int n_in,
                              void* d_out, int out_size, void* d_ws, size_t ws_size,
                              hipStream_t stream){
  (void)in_sizes; (void)n_in; (void)out_size;
  const float* x     = (const float*)d_in[0];
  const float* y     = (const float*)d_in[1];
  const float* mask  = (const float*)d_in[2];
  const float* wq_f  = (const float*)d_in[3];
  const float* bqkv  = (const float*)d_in[4];
  const float* wp_f  = (const float*)d_in[5];
  const float* bproj = (const float*)d_in[6];
  const float* btab  = (const float*)d_in[7];
  float* out = (float*)d_out;

  if (ws_size >= WS_NEED){
    unsigned short* wqf = (unsigned short*)((char*)d_ws + WQF_OFF);
    unsigned short* wpf = (unsigned short*)((char*)d_ws + WPF_OFF);
    float*          cmb = (float*)((char*)d_ws + COMB_OFF);
    hipLaunchKernelGGL(k0_wfrag,  dim3(252),  dim3(256), 0, stream, wq_f, wp_f, wqf, wpf);
    hipLaunchKernelGGL(prep_comb, dim3(6144), dim3(256), 0, stream, mask, btab, cmb);
    hipLaunchKernelGGL(k_fused,   dim3(2048), dim3(256), 0, stream,
                       x, y, wqf, wpf, bqkv, bproj, cmb, out);
  } else {
    unsigned short* wq  = (unsigned short*)d_ws;
    unsigned short* wp  = (unsigned short*)((char*)d_ws + FB_WP_OFF);
    float*          cmb = (float*)((char*)d_ws + FB_COMB_OFF);
    hipLaunchKernelGGL(prep_weights_fb, dim3(2016), dim3(256), 0, stream, wq_f, wp_f, wq, wp);
    hipLaunchKernelGGL(prep_comb,       dim3(6144), dim3(256), 0, stream, mask, btab, cmb);
    hipLaunchKernelGGL(fused_attn_fb,   dim3(2048), dim3(256), 0, stream,
                       x, y, bqkv, bproj, wq, wp, cmb, out);
  }
}